// Round 8
// baseline (325.362 us; speedup 1.0000x reference)
//
#include <hip/hip_runtime.h>
#include <math.h>

#define NTOK 4096
#define HDIM 1024
#define NEXP 8
#define IDIM 1408
#define TWO_I 2816
#define TK 64             // K-tile depth
#define NRB 40            // 256-row blocks: 8192 real + 8*255 pad <= 10240
#define ROWCAP (NRB * 256)

#define RT_BLKS 1024      // router blocks in moe_rcv
#define CVG_BLKS 2048     // gup-convert blocks in moe_rcv
#define G1_BLKS 880       // gemm blocks in moe_gemm1cd (8 XCD x 22 j x 5 r)
#define CVD_BLKS 256      // down-convert tail blocks in moe_gemm1cd

typedef _Float16 f16x8 __attribute__((ext_vector_type(8)));
typedef float f32x4 __attribute__((ext_vector_type(4)));

typedef __attribute__((address_space(1))) const unsigned int gu32;
typedef __attribute__((address_space(3))) unsigned int lu32;
__device__ __forceinline__ void async16(const void* g, void* l) {
  __builtin_amdgcn_global_load_lds((gu32*)g, (lu32*)l, 16, 0, 0);
}

// 256-aligned segment prefix from counts (uniform scalar work, once per block)
__device__ __forceinline__ void seg_prefix(const int* __restrict__ counts, int* aof) {
  int o = 0; aof[0] = 0;
#pragma unroll
  for (int i = 0; i < 8; i++) { o += (counts[i] + 255) & ~255; aof[i + 1] = o; }
}

__device__ __forceinline__ void cvt8(const float4* __restrict__ s, uint4* __restrict__ d, size_t idx) {
  float4 a = s[idx * 2], b = s[idx * 2 + 1];
  union { _Float16 h[8]; uint4 u; } p;
  p.h[0] = (_Float16)a.x; p.h[1] = (_Float16)a.y; p.h[2] = (_Float16)a.z; p.h[3] = (_Float16)a.w;
  p.h[4] = (_Float16)b.x; p.h[5] = (_Float16)b.y; p.h[6] = (_Float16)b.z; p.h[7] = (_Float16)b.w;
  d[idx] = p.u;
}

#define NG8 (NEXP * TWO_I * HDIM / 8)   // 2883584
#define ND8 (NEXP * HDIM * IDIM / 8)    // 1441792

// Fused: router (blocks 0..1023; one wave per token: fp32 logits, softmax, top-2,
// fp16 x write, per-BLOCK count partials in LDS — no global atomics) + gate_up
// fp32->fp16 convert (blocks 1024.., grid-stride). Partials transposed
// cnt_part[e*1024 + blk] so scatter can vector-sum.
extern "C" __global__ void moe_rcv(const float* __restrict__ x,
                                   const float* __restrict__ rw,
                                   int* __restrict__ topi,
                                   float* __restrict__ topw,
                                   _Float16* __restrict__ xh,
                                   int* __restrict__ cnt_part,
                                   const float* __restrict__ gup,
                                   _Float16* __restrict__ guph) {
  if (blockIdx.x >= RT_BLKS) {
    size_t idx = (size_t)(blockIdx.x - RT_BLKS) * 256 + threadIdx.x;
    const float4* s = (const float4*)gup; uint4* d = (uint4*)guph;
    for (; idx < NG8; idx += (size_t)CVG_BLKS * 256) cvt8(s, d, idx);
    return;
  }
  __shared__ int c8[NEXP];
  if (threadIdx.x < NEXP) c8[threadIdx.x] = 0;
  __syncthreads();
  int w = threadIdx.x >> 6, lane = threadIdx.x & 63;
  int t = blockIdx.x * 4 + w;
  const float4* xp = (const float4*)(x + (size_t)t * HDIM);
  const float4* rp = (const float4*)rw;
  float acc[NEXP];
#pragma unroll
  for (int e = 0; e < NEXP; e++) acc[e] = 0.f;
#pragma unroll
  for (int i = 0; i < HDIM / 256; i++) {  // 4 iters
    float4 xv = xp[i * 64 + lane];
    union { _Float16 h[4]; uint2 u; } pk;
    pk.h[0] = (_Float16)xv.x; pk.h[1] = (_Float16)xv.y;
    pk.h[2] = (_Float16)xv.z; pk.h[3] = (_Float16)xv.w;
    *(uint2*)(xh + (size_t)t * HDIM + i * 256 + lane * 4) = pk.u;
#pragma unroll
    for (int e = 0; e < NEXP; e++) {
      float4 rv = rp[e * 256 + i * 64 + lane];
      acc[e] += xv.x * rv.x + xv.y * rv.y + xv.z * rv.z + xv.w * rv.w;
    }
  }
#pragma unroll
  for (int e = 0; e < NEXP; e++) {
#pragma unroll
    for (int off = 32; off > 0; off >>= 1) acc[e] += __shfl_down(acc[e], off);
  }
  if (lane == 0) {
    float m = acc[0];
    for (int e = 1; e < NEXP; e++) m = fmaxf(m, acc[e]);
    float p[NEXP], s = 0.f;
    for (int e = 0; e < NEXP; e++) { p[e] = __expf(acc[e] - m); s += p[e]; }
    float inv = 1.f / s;
    int i0 = 0; float b0 = p[0];
    for (int e = 1; e < NEXP; e++) if (p[e] > b0) { b0 = p[e]; i0 = e; }
    int i1 = -1; float b1 = -1.f;
    for (int e = 0; e < NEXP; e++) if (e != i0 && p[e] > b1) { b1 = p[e]; i1 = e; }
    topi[t * 2] = i0; topi[t * 2 + 1] = i1;
    topw[t * 2] = b0 * inv; topw[t * 2 + 1] = b1 * inv;
    atomicAdd(&c8[i0], 1);   // LDS atomics only
    atomicAdd(&c8[i1], 1);
  }
  __syncthreads();
  if (threadIdx.x < NEXP) cnt_part[threadIdx.x * 1024 + blockIdx.x] = c8[threadIdx.x];
}

// deterministic scatter from 1024x8 partials: totals/aof/block-prefix computed
// locally; no cursor, no cross-block atomics. Block 0 publishes counts.
extern "C" __global__ void moe_scatter(const int* __restrict__ topi, const float* __restrict__ topw,
                                       const int* __restrict__ cnt_part, int* __restrict__ counts,
                                       int* __restrict__ tok, float* __restrict__ wrow,
                                       int* __restrict__ rows) {
  __shared__ int part16[16 * NEXP];
  __shared__ int cnt[NEXP];
  __shared__ int base[NEXP];
  __shared__ int tot_l[NEXP];
  const int tid = threadIdx.x, blk = blockIdx.x;
  if (tid < 128) {
    int g = tid >> 3, e = tid & 7;
    const int4* p = (const int4*)(cnt_part + e * 1024 + g * 64);
    int s = 0;
#pragma unroll
    for (int b = 0; b < 16; b++) { int4 v = p[b]; s += v.x + v.y + v.z + v.w; }
    part16[g * NEXP + e] = s;
  }
  if (tid < NEXP) cnt[tid] = 0;
  __syncthreads();
  if (tid < NEXP) {
    int tot = 0, pre = 0;
#pragma unroll
    for (int b = 0; b < 16; b++) {
      int v = part16[b * NEXP + tid];
      tot += v;
      if (b < blk) pre += v;
    }
    tot_l[tid] = tot;
    base[tid] = pre;
  }
  __syncthreads();
  if (tid < NEXP) {
    int o = 0;
    for (int i = 0; i < tid; i++) o += (tot_l[i] + 255) & ~255;   // aof[e]
    base[tid] += o;
    if (blk == 0) counts[tid] = tot_l[tid];
  }
  __syncthreads();
  int t = blk * 256 + tid;
  int e0 = topi[t * 2], e1 = topi[t * 2 + 1];
  int r0 = atomicAdd(&cnt[e0], 1);
  int r1 = atomicAdd(&cnt[e1], 1);
  int row0 = base[e0] + r0;
  int row1 = base[e1] + r1;
  tok[row0] = t; wrow[row0] = topw[t * 2];     rows[t * 2]     = row0;
  tok[row1] = t; wrow[row1] = topw[t * 2 + 1]; rows[t * 2 + 1] = row1;
}

// ---------------- 256x128 GEMM core: 8 waves (4x2), 64 KB LDS -> 2 blocks/CU ----------------
// Rationale (r0-r7 evidence): every 1-block/CU schedule plateaus at ~21% MfmaUtil
// because barrier-locked waves alternate LDS-port and MFMA-pipe phases. Two
// independent co-resident blocks run phase-shifted and fill each other's gaps.
// LDS: A single-buffer [256][64] 32 KB @0; B double-buffer 2x[128][64] @32 KB.
// A refill: reads complete (lgkm0) -> barrier -> DMA A(kt+1), hidden under MM(k1).
// VGPR budget: acc 64 + frags 32 + addr ~25 ~= 120; launch_bounds(512,4) caps 128
// so 2 blocks/CU holds (16 waves/CU). Swizzle: 16B chunk s of row r at s^(r&7),
// both-sides (pre-swizzled global source column kc + swizzled read addr).
#define WAITVM(n) asm volatile("s_waitcnt vmcnt(" #n ")" ::: "memory")
#define BAR() __builtin_amdgcn_s_barrier()
#define PRIO(x) __builtin_amdgcn_s_setprio(x)
#define LDV(off) (*(const f16x8*)((const char*)smem + (uint32_t)(off)))

#define K2_SETUP() \
  const int lane = tid & 63, wv = tid >> 6; \
  const int wm = wv >> 1, wn = wv & 1;            /* 4m x 2n, wave-tile 64x64 */ \
  const int quad = lane >> 4, l15 = lane & 15; \
  const int srow8 = tid >> 3;                      /* 0..63 */ \
  const int kc = ((tid & 7) ^ (srow8 & 7)) << 3;   /* swizzled 16B chunk, fp16 units */ \
  const uint32_t c0 = (uint32_t)((quad * 16) ^ ((l15 & 7) << 4)); \
  const uint32_t c1 = c0 ^ 64; \
  const uint32_t sA_0 = (uint32_t)((wm * 64 + l15) * 128) + c0; \
  const uint32_t sA_1 = (uint32_t)((wm * 64 + l15) * 128) + c1; \
  const uint32_t sB_0 = 32768u + (uint32_t)((wn * 64 + l15) * 128) + c0; \
  const uint32_t sB_1 = 32768u + (uint32_t)((wn * 64 + l15) * 128) + c1; \
  f32x4 acc2[4][4]; \
  _Pragma("unroll") for (int m = 0; m < 4; m++) \
  _Pragma("unroll") for (int n = 0; n < 4; n++) acc2[m][n] = (f32x4){0.f, 0.f, 0.f, 0.f}; \
  f16x8 va2[4], vb2[4];

// A: 4 async16/thread (rows c*64+srow8); dest linear tid*16B per 64-row group.
#define STGA(kt) { _Pragma("unroll") for (int c_ = 0; c_ < 4; c_++) \
  async16(pA2[c_] + (size_t)(kt) * TK, smem + c_ * 4096 + tid * 8); }
// B: 2 async16/thread; buf stride 16 KB.
#define STGB(kt, buf) { _Pragma("unroll") for (int c_ = 0; c_ < 2; c_++) \
  async16(pB2[c_] + (size_t)(kt) * TK, smem + 16384 + (buf) * 8192 + c_ * 4096 + tid * 8); }

#define K2_RDA(CS) { _Pragma("unroll") for (int m_ = 0; m_ < 4; m_++) va2[m_] = LDV((CS) + m_ * 2048); }
#define K2_RDB(CS) { _Pragma("unroll") for (int n_ = 0; n_ < 4; n_++) vb2[n_] = LDV((CS) + n_ * 2048); }
#define K2_MM() { _Pragma("unroll") for (int m_ = 0; m_ < 4; m_++) \
  _Pragma("unroll") for (int n_ = 0; n_ < 4; n_++) \
    acc2[m_][n_] = __builtin_amdgcn_mfma_f32_16x16x32_f16(va2[m_], vb2[n_], acc2[m_][n_], 0, 0, 0); }

#define K2_LOOP(NIT) { \
  STGA(0); STGB(0, 0); STGB(1, 1); \
  WAITVM(2); BAR(); \
  _Pragma("unroll 1") \
  for (int kt = 0; kt < (NIT); ++kt) { \
    const uint32_t bo = (uint32_t)(kt & 1) * 16384u; \
    K2_RDA(sA_0); K2_RDB(sB_0 + bo); \
    PRIO(1); K2_MM(); PRIO(0);                    /* compiler fine-grain lgkm waits */ \
    K2_RDA(sA_1); K2_RDB(sB_1 + bo); \
    asm volatile("s_waitcnt lgkmcnt(0)" ::: "memory");  /* reads landed in regs */ \
    __builtin_amdgcn_sched_barrier(0); \
    BAR();                                         /* all waves done with A(kt), B(kt) */ \
    if (kt + 1 < (NIT)) STGA(kt + 1);              /* refill A; hidden under MM(k1) */ \
    if (kt + 2 < (NIT)) STGB(kt + 2, (kt & 1)); \
    PRIO(1); K2_MM(); PRIO(0); \
    if (kt + 2 < (NIT)) { WAITVM(2); }             /* A(kt+1)+B(kt+1) done; B(kt+2) flies */ \
    else if (kt + 1 < (NIT)) { WAITVM(0); } \
    BAR(); \
  } }

// GEMM1 + down-convert tail. Tile: 256 rows x (64 gate + 64 up rows of the same
// 64 h-cols) -> silu block-local. Grid 880 = 8 XCD x (22 j x 5 r), rb = g + 8*r
// (round-5 best mapping); blocks 880.. grid-stride convert down_proj.
extern "C" __global__ __launch_bounds__(512, 4) void moe_gemm1cd(
    const _Float16* __restrict__ xh, const _Float16* __restrict__ guph,
    const int* __restrict__ counts, const int* __restrict__ tok,
    _Float16* __restrict__ hbuf,
    const float* __restrict__ dp, _Float16* __restrict__ dph) {
  __shared__ __align__(128) _Float16 smem[32768];  // 64 KiB
  const int tid = threadIdx.x;
  const int fid = blockIdx.x;
  if (fid >= G1_BLKS) {
    size_t idx = (size_t)(fid - G1_BLKS) * 512 + tid;
    const float4* s = (const float4*)dp; uint4* d = (uint4*)dph;
    for (; idx < ND8; idx += (size_t)CVD_BLKS * 512) cvt8(s, d, idx);
    return;
  }
  int aof[9]; seg_prefix(counts, aof);
  const int g = fid & 7, idx = fid >> 3;    // idx in [0,110)
  const int j = idx / 5, r = idx - j * 5;   // j 0..21, r 0..4
  const int rb = g + 8 * r;                 // 0..39
  const int row0 = rb * 256;
  if (row0 >= aof[8]) return;
  int e = 0;
#pragma unroll
  for (int i = 0; i < 8; i++) if (row0 >= aof[i]) e = i;
  const int lim = aof[e] + counts[e];       // rows >= lim are pad

  K2_SETUP();

  const _Float16* pA2[4]; const _Float16* pB2[2];
#pragma unroll
  for (int c = 0; c < 4; c++) {
    int rowi = row0 + c * 64 + srow8;
    int tv = tok[rowi];                 // in-bounds always; garbage on pad rows
    int tk = (rowi < lim) ? tv : 0;     // pad rows clamp; outputs discarded
    pA2[c] = xh + (size_t)tk * HDIM + kc;
  }
  const _Float16* eb = guph + (size_t)e * TWO_I * HDIM;
  pB2[0] = eb + (size_t)(j * 64 + srow8) * HDIM + kc;          // gate rows -> B rows 0..63
  pB2[1] = eb + (size_t)(IDIM + j * 64 + srow8) * HDIM + kc;   // up rows   -> B rows 64..127

  K2_LOOP(HDIM / TK)   // 16 K-tiles

  // epilogue: wn=1 (up) parks u in LDS; wn=0 (gate) computes silu(g)*u
  if (wn == 1) {
#pragma unroll
    for (int mf = 0; mf < 4; mf++)
#pragma unroll
      for (int nf = 0; nf < 4; nf++)
#pragma unroll
        for (int r2 = 0; r2 < 4; r2++)
          smem[(wm * 64 + mf * 16 + quad * 4 + r2) * 66 + nf * 16 + l15] =
              (_Float16)acc2[mf][nf][r2];
  }
  __syncthreads();
  if (wn == 0) {
#pragma unroll
    for (int mf = 0; mf < 4; mf++) {
#pragma unroll
      for (int r2 = 0; r2 < 4; r2++) {
        const int rl = wm * 64 + mf * 16 + quad * 4 + r2;
        _Float16* orow = hbuf + (size_t)(row0 + rl) * IDIM + j * 64;
#pragma unroll
        for (int nf = 0; nf < 4; nf++) {
          float gg = acc2[mf][nf][r2];
          float uu = (float)smem[rl * 66 + nf * 16 + l15];
          float hh = gg / (1.f + __expf(-gg)) * uu;
          orow[nf * 16 + l15] = (_Float16)hh;
        }
      }
    }
  }
}

// GEMM2: y[row, 1024] = (h @ down[e]^T) * wrow[row]; same 256x128 core.
// Grid 320 = 8 XCD x (8 cb x 5 r); rb = g + 8*r.
extern "C" __global__ __launch_bounds__(512, 4) void moe_gemm2(
    const _Float16* __restrict__ hbuf, const _Float16* __restrict__ dph,
    const int* __restrict__ counts, const float* __restrict__ wrow,
    _Float16* __restrict__ yh) {
  __shared__ __align__(128) _Float16 smem[32768];  // 64 KiB
  int aof[9]; seg_prefix(counts, aof);
  const int tid = threadIdx.x;
  const int fid = blockIdx.x;
  const int g = fid & 7, idx = fid >> 3;    // idx in [0,40)
  const int cb = idx / 5, r = idx - cb * 5; // cb 0..7
  const int rb = g + 8 * r;                 // 0..39
  const int row0 = rb * 256;
  if (row0 >= aof[8]) return;
  int e = 0;
#pragma unroll
  for (int i = 0; i < 8; i++) if (row0 >= aof[i]) e = i;

  K2_SETUP();

  const _Float16* pA2[4]; const _Float16* pB2[2];
#pragma unroll
  for (int c = 0; c < 4; c++)
    pA2[c] = hbuf + (size_t)(row0 + c * 64 + srow8) * IDIM + kc;
  const _Float16* eb = dph + (size_t)e * HDIM * IDIM;
  pB2[0] = eb + (size_t)(cb * 128 + srow8) * IDIM + kc;
  pB2[1] = eb + (size_t)(cb * 128 + 64 + srow8) * IDIM + kc;

  K2_LOOP(IDIM / TK)   // 22 K-tiles

#pragma unroll
  for (int mf = 0; mf < 4; mf++) {
#pragma unroll
    for (int r2 = 0; r2 < 4; r2++) {
      const int row = row0 + wm * 64 + mf * 16 + quad * 4 + r2;
      const float wgt = wrow[row];  // pad rows: garbage weight, rows never read back
      _Float16* orow = yh + (size_t)row * HDIM + cb * 128 + wn * 64;
#pragma unroll
      for (int nf = 0; nf < 4; nf++)
        orow[nf * 16 + l15] = (_Float16)(acc2[mf][nf][r2] * wgt);
    }
  }
}

// out[t, :] = y[rowA(t), :] + y[rowB(t), :]
extern "C" __global__ void moe_combine(const _Float16* __restrict__ yh,
                                       const int* __restrict__ rows,
                                       float* __restrict__ out) {
  int i = blockIdx.x * 256 + threadIdx.x;  // over T*H/8 = 524288
  int t = i >> 7, c8 = i & 127;
  int rA = rows[t * 2], rB = rows[t * 2 + 1];
  union { uint4 u; _Float16 h[8]; } pa, pb;
  pa.u = ((const uint4*)(yh + (size_t)rA * HDIM))[c8];
  pb.u = ((const uint4*)(yh + (size_t)rB * HDIM))[c8];
  float4 o0, o1;
  o0.x = (float)pa.h[0] + (float)pb.h[0]; o0.y = (float)pa.h[1] + (float)pb.h[1];
  o0.z = (float)pa.h[2] + (float)pb.h[2]; o0.w = (float)pa.h[3] + (float)pb.h[3];
  o1.x = (float)pa.h[4] + (float)pb.h[4]; o1.y = (float)pa.h[5] + (float)pb.h[5];
  o1.z = (float)pa.h[6] + (float)pb.h[6]; o1.w = (float)pa.h[7] + (float)pb.h[7];
  ((float4*)out)[(size_t)i * 2] = o0;
  ((float4*)out)[(size_t)i * 2 + 1] = o1;
}

extern "C" void kernel_launch(void* const* d_in, const int* in_sizes, int n_in,
                              void* d_out, int out_size, void* d_ws, size_t ws_size,
                              hipStream_t stream) {
  const float* x   = (const float*)d_in[0];  // [4096,1024]
  const float* rw  = (const float*)d_in[1];  // [8,1024]
  const float* gup = (const float*)d_in[2];  // [8,2816,1024]
  const float* dp  = (const float*)d_in[3];  // [8,1024,1408]
  float* out = (float*)d_out;

  char* ws = (char*)d_ws;
  int*   counts   = (int*)ws;                     // 8 ints      @0
  int*   cnt_part = (int*)(ws + 64);              // 8x1024 ints -> 32832
  int*   topi   = (int*)(ws + 32832);             // 8192 ints   -> 65600
  float* topw   = (float*)(ws + 65600);           // 8192 floats -> 98368
  int*   tok    = (int*)(ws + 98368);             // 10240 ints  -> 139328
  float* wrow   = (float*)(ws + 139328);          // 10240 floats-> 180288
  int*   rows   = (int*)(ws + 180288);            // 8192 ints   -> 213056
  _Float16* xh   = (_Float16*)(ws + 213056);      // 8.39 MB  -> 8601664
  _Float16* guph = (_Float16*)(ws + 8601664);     // 46.14 MB -> 54739008
  _Float16* dph  = (_Float16*)(ws + 54739008);    // 23.07 MB -> 77807680
  _Float16* hbuf = (_Float16*)(ws + 77807680);    // 28.84 MB -> 106643520 (total 106.6 MB)
  _Float16* yh   = (_Float16*)(ws + 8601664);     // aliases guph (dead after gemm1)

  moe_rcv<<<RT_BLKS + CVG_BLKS, 256, 0, stream>>>(x, rw, topi, topw, xh, cnt_part, gup, guph);
  moe_scatter<<<NTOK / 256, 256, 0, stream>>>(topi, topw, cnt_part, counts, tok, wrow, rows);
  moe_gemm1cd<<<G1_BLKS + CVD_BLKS, 512, 0, stream>>>(xh, guph, counts, tok, hbuf, dp, dph);
  moe_gemm2<<<8 * 8 * 5, 512, 0, stream>>>(hbuf, dph, counts, wrow, yh);
  moe_combine<<<NTOK * HDIM / 8 / 256, 256, 0, stream>>>(yh, rows, out);
}